// Round 6
// baseline (148.595 us; speedup 1.0000x reference)
//
#include <hip/hip_runtime.h>
#include <hip/hip_cooperative_groups.h>
#include <math.h>

namespace cg = cooperative_groups;

#define NBLK 512   // 512 blocks x 4 waves; each wave owns 2 rows (sequential)

// ws (uint cells): [0]=raw-max key, [1]=filtered-min key, [2]=raw-min key
// monotone order-preserving float<->uint key
__device__ __forceinline__ unsigned f2key(float f){
  unsigned b = __float_as_uint(f);
  return (b & 0x80000000u) ? ~b : (b | 0x80000000u);
}
__device__ __forceinline__ float key2f(unsigned k){
  unsigned b = (k & 0x80000000u) ? (k ^ 0x80000000u) : ~k;
  return __uint_as_float(b);
}

__device__ __forceinline__ float wred_max(float x){
  #pragma unroll
  for (int m = 32; m; m >>= 1) x = fmaxf(x, __shfl_xor(x, m, 64));
  return x;
}
__device__ __forceinline__ float wred_min(float x){
  #pragma unroll
  for (int m = 32; m; m >>= 1) x = fminf(x, __shfl_xor(x, m, 64));
  return x;
}
__device__ __forceinline__ float wred_sum(float x){
  #pragma unroll
  for (int m = 32; m; m >>= 1) x += __shfl_xor(x, m, 64);
  return x;
}

// 1/a0+1/a1+1/a2+1/a3 with one v_rcp. By value (no pointers into local
// arrays -- the R3 scratch-spill trap).
__device__ __forceinline__ float batch4(float a0, float a1, float a2, float a3){
  float m01 = a0 * a1, m23 = a2 * a3;
  float num = fmaf(m01, a2 + a3, m23 * (a0 + a1));
  return num * __builtin_amdgcn_rcpf(m01 * m23);
}

__global__ __launch_bounds__(256)
void k_fused(const float* __restrict__ scores, float* __restrict__ out,
             unsigned* __restrict__ ws){
  const int wid  = threadIdx.x >> 6;
  const int lane = threadIdx.x & 63;

  // ---- Phase A: streaming grid-stride minmax over all 2M float4 ----
  {
    const float4* __restrict__ s4 = (const float4*)scores;
    const int tid = blockIdx.x * 256 + threadIdx.x;
    float mx = -INFINITY, fmn = INFINITY, rmn = INFINITY;
    #pragma unroll
    for (int k = 0; k < 16; ++k){          // 2M / (512*256) = 16
      float4 v = s4[tid + k * (NBLK * 256)];
      float c[4] = {v.x, v.y, v.z, v.w};
      #pragma unroll
      for (int j = 0; j < 4; ++j){
        float x = c[j];
        mx  = fmaxf(mx, x);
        rmn = fminf(rmn, x);
        fmn = fminf(fmn, (x == -INFINITY) ? INFINITY : x);
      }
    }
    mx = wred_max(mx); fmn = wred_min(fmn); rmn = wred_min(rmn);
    __shared__ float sm[12];
    if (lane == 0){ sm[wid] = mx; sm[4 + wid] = fmn; sm[8 + wid] = rmn; }
    __syncthreads();
    if (threadIdx.x == 0){
      float a = fmaxf(fmaxf(sm[0], sm[1]), fmaxf(sm[2], sm[3]));
      float b = fminf(fminf(sm[4], sm[5]), fminf(sm[6], sm[7]));
      float c = fminf(fminf(sm[8], sm[9]), fminf(sm[10], sm[11]));
      atomicMax(&ws[0], f2key(a));
      atomicMin(&ws[1], f2key(b));
      atomicMin(&ws[2], f2key(c));
    }
  }

  cg::this_grid().sync();

  // ---- Phase B: constants (recomputed per thread, ~20 ops) ----
  float max_s = key2f(__hip_atomic_load(&ws[0], __ATOMIC_RELAXED, __HIP_MEMORY_SCOPE_AGENT));
  float min_s = key2f(__hip_atomic_load(&ws[1], __ATOMIC_RELAXED, __HIP_MEMORY_SCOPE_AGENT));
  float rmin  = key2f(__hip_atomic_load(&ws[2], __ATOMIC_RELAXED, __HIP_MEMORY_SCOPE_AGENT));
  const float filled = min_s - (max_s - min_s);
  float lo = (rmin == -INFINITY) ? filled : min_s;
  float hi = max_s;
  float cmax = fmaxf(fmaxf(lo * lo, (lo - 1.f) * (lo - 1.f)),
                     fmaxf(hi * hi, (hi - 1.f) * (hi - 1.f)));
  float invX = 1.0f / (cmax * 0.1f);           // 1/(Cmax*EPS)
  float cc = 1.4426950408889634f * invX;       // log2(e)/(Cmax*EPS)
  const float cA = 2.0f * cc, cB = -cc;

  // ---- Phase C: two rows per wave, strictly sequential (32 live floats) ----
  #pragma unroll 1
  for (int rr = 0; rr < 2; ++rr){
    const int row = (blockIdx.x * 4 + wid) * 2 + rr;
    const float4* __restrict__ src = (const float4*)(scores + (size_t)row * 2048);

    // load (L3-warm after phase A) and transform: r = exp2(s*cA+cB) = G1/G0
    float s[32];
    #pragma unroll
    for (int k = 0; k < 8; ++k){
      float4 v = src[k * 64 + lane];
      float c[4] = {v.x, v.y, v.z, v.w};
      #pragma unroll
      for (int j = 0; j < 4; ++j){
        float x = c[j];
        if (x == -INFINITY) x = filled;
        s[4*k+j] = __builtin_amdgcn_exp2f(fmaf(x, cA, cB));
      }
    }

    // scalar Sinkhorn: t = v0/v1; P(t) = t * sum 1/(t+r); fixed point P = K.
    // t' = t*(K/(n-K))*(n-P)/P; contraction ~0.03/iter; tol > 1 ulp of t.
    float t = 1.0f, P = 0.0f;
    int it = 0;
    while (true){
      float acc0 = 0.f, acc1 = 0.f;
      #pragma unroll
      for (int g = 0; g < 8; g += 2){
        acc0 += batch4(t + s[4*g+0], t + s[4*g+1], t + s[4*g+2], t + s[4*g+3]);
        acc1 += batch4(t + s[4*g+4], t + s[4*g+5], t + s[4*g+6], t + s[4*g+7]);
      }
      float acc = wred_sum(acc0 + acc1);
      P = t * acc;
      if (++it == 50) break;
      float tn = t * (2048.0f - P) * 0.0322580645161f * __builtin_amdgcn_rcpf(P);
      if (fabsf(tn - t) <= 1e-6f * t) break;   // fixed point: further iters no-ops
      t = tn;
    }

    // epilogue: A_i = c0/(t+r_i), 1 rcp per 4 outputs
    const float c0 = 64.0f * t * __builtin_amdgcn_rcpf(P);
    float4* __restrict__ dst = (float4*)(out + (size_t)row * 2048);
    #pragma unroll
    for (int k = 0; k < 8; ++k){
      float a0 = t + s[4*k+0], a1 = t + s[4*k+1];
      float a2 = t + s[4*k+2], a3 = t + s[4*k+3];
      float m01 = a0 * a1, m23 = a2 * a3;
      float e = c0 * __builtin_amdgcn_rcpf(m01 * m23);
      float4 o;
      o.x = a1 * m23 * e;
      o.y = a0 * m23 * e;
      o.z = a3 * m01 * e;
      o.w = a2 * m01 * e;
      dst[k * 64 + lane] = o;
    }
  }
}

extern "C" void kernel_launch(void* const* d_in, const int* in_sizes, int n_in,
                              void* d_out, int out_size, void* d_ws, size_t ws_size,
                              hipStream_t stream) {
  const float* scores = (const float*)d_in[0];
  float* out = (float*)d_out;
  unsigned* ws = (unsigned*)d_ws;

  // init atomic cells: max key -> 0x00000000, min keys -> 0xFFFFFFFF
  hipMemsetAsync(ws,     0x00, 4, stream);
  hipMemsetAsync(ws + 1, 0xFF, 8, stream);

  void* args[] = { (void*)&scores, (void*)&out, (void*)&ws };
  hipLaunchCooperativeKernel((void*)k_fused, dim3(NBLK), dim3(256), args, 0, stream);
}

// Round 7
// 91.543 us; speedup vs baseline: 1.6232x; 1.6232x over previous
//
#include <hip/hip_runtime.h>
#include <math.h>

// ws layout (floats):
// [0..1024)      per-block raw max partials
// [1024..2048)   per-block filtered min (-inf -> +inf) partials
// [2048..3072)   per-block raw min partials
#define NB_MM   1024
#define WS_MAX  0
#define WS_FMIN 1024
#define WS_RMIN 2048

__device__ __forceinline__ float wred_max(float x){
  #pragma unroll
  for (int m = 32; m; m >>= 1) x = fmaxf(x, __shfl_xor(x, m, 64));
  return x;
}
__device__ __forceinline__ float wred_min(float x){
  #pragma unroll
  for (int m = 32; m; m >>= 1) x = fminf(x, __shfl_xor(x, m, 64));
  return x;
}
__device__ __forceinline__ float wred_sum(float x){
  #pragma unroll
  for (int m = 32; m; m >>= 1) x += __shfl_xor(x, m, 64);
  return x;
}

// 1/a0+1/a1+1/a2+1/a3 with one v_rcp. By value (no pointers into local
// arrays -- the R3 scratch-spill trap).
__device__ __forceinline__ float batch4(float a0, float a1, float a2, float a3){
  float m01 = a0 * a1, m23 = a2 * a3;
  float num = fmaf(m01, a2 + a3, m23 * (a0 + a1));
  return num * __builtin_amdgcn_rcpf(m01 * m23);
}

// Pass 1: per-block {raw max, filtered min, raw min} partials over all scores.
__global__ __launch_bounds__(256) void k_minmax(const float4* __restrict__ s4,
                                                int n4, float* __restrict__ ws){
  int tid = blockIdx.x * 256 + threadIdx.x;
  float mx = -INFINITY, fmn = INFINITY, rmn = INFINITY;
  for (int i = tid; i < n4; i += NB_MM * 256){
    float4 v = s4[i];
    float c[4] = {v.x, v.y, v.z, v.w};
    #pragma unroll
    for (int j = 0; j < 4; ++j){
      float s = c[j];
      mx  = fmaxf(mx, s);
      rmn = fminf(rmn, s);
      fmn = fminf(fmn, (s == -INFINITY) ? INFINITY : s);
    }
  }
  mx = wred_max(mx); fmn = wred_min(fmn); rmn = wred_min(rmn);
  __shared__ float sm[12];
  int w = threadIdx.x >> 6;
  if ((threadIdx.x & 63) == 0){ sm[w] = mx; sm[4 + w] = fmn; sm[8 + w] = rmn; }
  __syncthreads();
  if (threadIdx.x == 0){
    ws[WS_MAX  + blockIdx.x] = fmaxf(fmaxf(sm[0], sm[1]), fmaxf(sm[2], sm[3]));
    ws[WS_FMIN + blockIdx.x] = fminf(fminf(sm[4], sm[5]), fminf(sm[6], sm[7]));
    ws[WS_RMIN + blockIdx.x] = fminf(fminf(sm[8], sm[9]), fminf(sm[10], sm[11]));
  }
}

// Pass 2 (fused finalize + sinkhorn): each block re-folds the 1024 partials
// (L2-hot, one float4 per thread per array), computes the constants, then
// runs one row per wave exactly as R4.
__global__ __launch_bounds__(256) void k_main(const float* __restrict__ scores,
                                              float* __restrict__ out,
                                              const float* __restrict__ ws){
  const int wid  = threadIdx.x >> 6;
  const int lane = threadIdx.x & 63;

  // ---- prologue: fold partials -> (max_s, min_s, rmin) ----
  __shared__ float sm[12];
  {
    const float4* pmx = (const float4*)(ws + WS_MAX);
    const float4* pfm = (const float4*)(ws + WS_FMIN);
    const float4* prm = (const float4*)(ws + WS_RMIN);
    float4 a = pmx[threadIdx.x];
    float4 b = pfm[threadIdx.x];
    float4 c = prm[threadIdx.x];
    float mx  = fmaxf(fmaxf(a.x, a.y), fmaxf(a.z, a.w));
    float fmn = fminf(fminf(b.x, b.y), fminf(b.z, b.w));
    float rmn = fminf(fminf(c.x, c.y), fminf(c.z, c.w));
    mx = wred_max(mx); fmn = wred_min(fmn); rmn = wred_min(rmn);
    if (lane == 0){ sm[wid] = mx; sm[4 + wid] = fmn; sm[8 + wid] = rmn; }
  }
  __syncthreads();
  const float max_s = fmaxf(fmaxf(sm[0], sm[1]), fmaxf(sm[2], sm[3]));
  const float min_s = fminf(fminf(sm[4], sm[5]), fminf(sm[6], sm[7]));
  const float rmin  = fminf(fminf(sm[8], sm[9]), fminf(sm[10], sm[11]));

  // constants (per thread, ~20 ops)
  // Cmax = max over data of max(s^2,(s-1)^2); convex => attained at extremes.
  const float filled = min_s - (max_s - min_s);
  float lo = (rmin == -INFINITY) ? filled : min_s;
  float hi = max_s;
  float cmax = fmaxf(fmaxf(lo * lo, (lo - 1.f) * (lo - 1.f)),
                     fmaxf(hi * hi, (hi - 1.f) * (hi - 1.f)));
  float invX = 1.0f / (cmax * 0.1f);           // 1/(Cmax*EPS)
  float cc = 1.4426950408889634f * invX;       // log2(e)/(Cmax*EPS)
  const float cA = 2.0f * cc, cB = -cc;

  // ---- one row per wave (proven R4 body) ----
  const int row  = blockIdx.x * 4 + wid;
  const float4* __restrict__ src = (const float4*)(scores + (size_t)row * 2048);

  // load (L3-warm after pass 1) and transform: r = exp2(s*cA+cB) = G1/G0
  float s[32];
  #pragma unroll
  for (int k = 0; k < 8; ++k){
    float4 v = src[k * 64 + lane];
    float c[4] = {v.x, v.y, v.z, v.w};
    #pragma unroll
    for (int j = 0; j < 4; ++j){
      float x = c[j];
      if (x == -INFINITY) x = filled;
      s[4*k+j] = __builtin_amdgcn_exp2f(fmaf(x, cA, cB));
    }
  }

  // scalar Sinkhorn: t = v0/v1; P(t) = t * sum 1/(t+r); fixed point P = K.
  // t' = t*(K/(n-K))*(n-P)/P; exit tol 1e-6*t (> 1 ulp limit cycle).
  float t = 1.0f, P = 0.0f;
  int it = 0;
  while (true){
    float acc0 = 0.f, acc1 = 0.f;
    #pragma unroll
    for (int g = 0; g < 8; g += 2){
      acc0 += batch4(t + s[4*g+0], t + s[4*g+1], t + s[4*g+2], t + s[4*g+3]);
      acc1 += batch4(t + s[4*g+4], t + s[4*g+5], t + s[4*g+6], t + s[4*g+7]);
    }
    float acc = wred_sum(acc0 + acc1);
    P = t * acc;
    if (++it == 50) break;
    float tn = t * (2048.0f - P) * 0.0322580645161f * __builtin_amdgcn_rcpf(P);
    if (fabsf(tn - t) <= 1e-6f * t) break;   // fixed point: further iters no-ops
    t = tn;
  }

  // epilogue: A_i = c0/(t+r_i), 1 rcp per 4 outputs
  const float c0 = 64.0f * t * __builtin_amdgcn_rcpf(P);
  float4* __restrict__ dst = (float4*)(out + (size_t)row * 2048);
  #pragma unroll
  for (int k = 0; k < 8; ++k){
    float a0 = t + s[4*k+0], a1 = t + s[4*k+1];
    float a2 = t + s[4*k+2], a3 = t + s[4*k+3];
    float m01 = a0 * a1, m23 = a2 * a3;
    float e = c0 * __builtin_amdgcn_rcpf(m01 * m23);
    float4 o;
    o.x = a1 * m23 * e;
    o.y = a0 * m23 * e;
    o.z = a3 * m01 * e;
    o.w = a2 * m01 * e;
    dst[k * 64 + lane] = o;
  }
}

extern "C" void kernel_launch(void* const* d_in, const int* in_sizes, int n_in,
                              void* d_out, int out_size, void* d_ws, size_t ws_size,
                              hipStream_t stream) {
  const float* scores = (const float*)d_in[0];
  float* out = (float*)d_out;
  float* ws  = (float*)d_ws;
  const int n4 = in_sizes[0] / 4;

  k_minmax<<<NB_MM, 256, 0, stream>>>((const float4*)scores, n4, ws);
  k_main  <<<1024,  256, 0, stream>>>(scores, out, ws);
}